// Round 7
// baseline (238.705 us; speedup 1.0000x reference)
//
#include <hip/hip_runtime.h>
#include <math.h>

#define BB     1024
#define CC     256
#define HWN    361
#define SEH    64
#define P3C    768
#define SLICE  (CC * HWN)     // 92416 floats per batch row
#define NW     16             // waves per block

// One block (16 waves) per batch row b; 1 block/CU (VGPR<=128).
// Wave wv owns rows wv*16..wv*16+15. x is loaded ONCE into registers
// (vv[16][6], 90.25 f32/lane), pooled, held across the in-LDS MLP, and
// applied+stored from registers. x never re-read.
__global__ __launch_bounds__(1024, 4) void k_se_fused(
        const float* __restrict__ x,
        const float* __restrict__ mask,
        const float* __restrict__ msum,
        const float* __restrict__ msqrt,
        const float* __restrict__ w1,
        const float* __restrict__ b1,
        const float* __restrict__ w2,
        const float* __restrict__ b2,
        float* __restrict__ out) {
    __shared__ float m_s[HWN];
    __shared__ float p_s[P3C];
    __shared__ float part_s[NW * SEH];
    __shared__ float hid_s[SEH];
    __shared__ float g_s[CC];
    __shared__ float be_s[CC];

    const int tid  = threadIdx.x;
    const int lane = tid & 63;
    const int wv   = tid >> 6;          // 0..15
    const int b    = blockIdx.x;

    const float* xb = x + (size_t)b * SLICE;

    if (tid < HWN) m_s[tid] = mask[(size_t)b * HWN + tid];
    __syncthreads();

    const float inv_div = 1.0f / msum[b];
    const float bscale  = (msqrt[b] - 14.0f) * 0.1f;   // (sqrt(div)-B_AVG)/10

    float vv[16][6];                    // statically indexed only

    // ---- pool + retain: 2 rows per pass (4 interleaved shuffle chains) ----
    #pragma unroll
    for (int kp = 0; kp < 16; kp += 2) {
        const int c0 = wv * 16 + kp;
        const float* r0 = xb + c0 * HWN;
        const float* r1 = r0 + HWN;
        #pragma unroll
        for (int ii = 0; ii < 5; ++ii) {
            const int i = lane + ii * 64;
            vv[kp    ][ii] = r0[i];
            vv[kp + 1][ii] = r1[i];
        }
        if (lane < 41) {                 // 361 = 5*64 + 41
            vv[kp    ][5] = r0[lane + 320];
            vv[kp + 1][5] = r1[lane + 320];
        }
        float s0 = 0.0f, s1 = 0.0f, x0 = -INFINITY, x1 = -INFINITY;
        #pragma unroll
        for (int ii = 0; ii < 5; ++ii) {
            const int i = lane + ii * 64;
            const float pen = (1.0f - m_s[i]) * -5000.0f;
            s0 += vv[kp][ii];     x0 = fmaxf(x0, vv[kp][ii] + pen);
            s1 += vv[kp + 1][ii]; x1 = fmaxf(x1, vv[kp + 1][ii] + pen);
        }
        if (lane < 41) {
            const float pen = (1.0f - m_s[lane + 320]) * -5000.0f;
            s0 += vv[kp][5];      x0 = fmaxf(x0, vv[kp][5] + pen);
            s1 += vv[kp + 1][5];  x1 = fmaxf(x1, vv[kp + 1][5] + pen);
        }
        #pragma unroll
        for (int off = 32; off; off >>= 1) {
            s0 += __shfl_xor(s0, off);  x0 = fmaxf(x0, __shfl_xor(x0, off));
            s1 += __shfl_xor(s1, off);  x1 = fmaxf(x1, __shfl_xor(x1, off));
        }
        if (lane == 0) {
            const float mean0 = s0 * inv_div, mean1 = s1 * inv_div;
            p_s[c0]           = mean0;
            p_s[256 + c0]     = mean0 * bscale;
            p_s[512 + c0]     = x0;
            p_s[c0 + 1]       = mean1;
            p_s[256 + c0 + 1] = mean1 * bscale;
            p_s[512 + c0 + 1] = x1;
        }
    }
    __syncthreads();

    // ---- layer 1 (768 -> 64): 16 partials (48 long) per output ----
    {
        const int q = tid >> 6, s = tid & 63;
        const float* w1r = w1  + s * P3C + q * 48;
        const float* pp  = p_s + q * 48;
        float acc = 0.0f;
        #pragma unroll 8
        for (int j = 0; j < 48; ++j) acc = fmaf(pp[j], w1r[j], acc);
        part_s[q * SEH + s] = acc;
    }
    __syncthreads();
    if (tid < SEH) {
        float h = b1[tid];
        #pragma unroll
        for (int q = 0; q < NW; ++q) h += part_s[q * SEH + tid];
        hid_s[tid] = fmaxf(h, 0.0f);
    }
    __syncthreads();

    // ---- layer 2 (64 -> 512) ----
    if (tid < 512) {
        float a = b2[tid];
        const float* w2r = w2 + (size_t)tid * SEH;
        #pragma unroll 8
        for (int ss = 0; ss < SEH; ++ss) a = fmaf(hid_s[ss], w2r[ss], a);
        if (tid < 256) g_s[tid]        = 1.0f / (1.0f + __expf(-a));
        else           be_s[tid - 256] = a;
    }
    __syncthreads();

    // ---- apply from registers; c is loop-static -> LDS broadcasts ----
    float* ob = out + (size_t)b * SLICE;
    #pragma unroll
    for (int k = 0; k < 16; ++k) {
        const int c  = wv * 16 + k;
        const float g  = g_s[c];
        const float be = be_s[c];
        float* orow = ob + c * HWN;
        #pragma unroll
        for (int ii = 0; ii < 5; ++ii) {
            const int i = lane + ii * 64;
            __builtin_nontemporal_store(fmaf(g, vv[k][ii], be) * m_s[i], &orow[i]);
        }
        if (lane < 41) {
            const int i = lane + 320;
            __builtin_nontemporal_store(fmaf(g, vv[k][5], be) * m_s[i], &orow[i]);
        }
    }
}

extern "C" void kernel_launch(void* const* d_in, const int* in_sizes, int n_in,
                              void* d_out, int out_size, void* d_ws, size_t ws_size,
                              hipStream_t stream) {
    const float* x     = (const float*)d_in[0];
    const float* mask  = (const float*)d_in[1];
    const float* msum  = (const float*)d_in[2];
    const float* msqrt = (const float*)d_in[3];
    const float* w1    = (const float*)d_in[4];
    const float* b1    = (const float*)d_in[5];
    const float* w2    = (const float*)d_in[6];
    const float* b2    = (const float*)d_in[7];
    float* out = (float*)d_out;

    k_se_fused<<<BB, 1024, 0, stream>>>(x, mask, msum, msqrt, w1, b1, w2, b2, out);
}